// Round 3
// baseline (5487.387 us; speedup 1.0000x reference)
//
#include <hip/hip_runtime.h>

#define WAVE 64

// ---------------------------------------------------------------------------
// split pointcloud (B,N,6) -> xyz (B,N,3) + feats (B,N,3)
__global__ __launch_bounds__(256) void split_kernel(const float* __restrict__ pc,
    float* __restrict__ xyz, float* __restrict__ feats, int total) {
  int t = blockIdx.x * blockDim.x + threadIdx.x;
  if (t >= total) return;
  const float* p = pc + (size_t)t * 6;
  xyz[t * 3 + 0] = p[0]; xyz[t * 3 + 1] = p[1]; xyz[t * 3 + 2] = p[2];
  feats[t * 3 + 0] = p[3]; feats[t * 3 + 1] = p[4]; feats[t * 3 + 2] = p[5];
}

__global__ __launch_bounds__(256) void zero_kernel(float* __restrict__ p, int n) {
  int t = blockIdx.x * blockDim.x + threadIdx.x;
  if (t < n) p[t] = 0.f;
}

// ---------------------------------------------------------------------------
// Farthest point sampling, one block per batch.
// Round-2 post-mortem: compiler refused to keep the 64-float point state in
// VGPRs (VGPR_Count=56 both with and without launch_bounds) -> spill/remat.
// This version makes the per-iteration point reads INTENTIONAL: prologue
// builds planar per-batch xy(float2)+z arrays in ws; every iteration streams
// them from L2 (coalesced, ~196KB/iter/CU ~ overlapped with the VALU floor).
// Only mind[P] lives in registers (~40 VGPRs total -> no spill at any cap).
// Reduction: per-wave u64 butterfly -> lane0 atomicMax into an LDS slot
// (3-slot rotation: the reset of a slot is a full barrier away from its last
// read) -> ONE barrier/iter; winner coords re-read from planar arrays
// (same-address broadcast load).
// Exact rounding: ((dx*dx+dy*dy)+dz*dz) with explicit _rn ops; tie-break =
// smallest index via key = (valbits<<32) | (0xFFFFFFFF - idx), max-reduced.
template<int P>
__global__ __launch_bounds__(1024) void fps_kernel(const float* __restrict__ xyz,
    float* __restrict__ new_xyz, float2* __restrict__ xys, float* __restrict__ zs,
    int N, int S) {
  const int b = blockIdx.x;
  const int T = blockDim.x;
  const int tid = threadIdx.x;
  const int lane = tid & 63;
  const float* px = xyz + (size_t)b * N * 3;
  float2* bxy = xys + (size_t)b * N;
  float* bz = zs + (size_t)b * N;
  __shared__ unsigned long long s_key[3];
  float mind[P];
#pragma unroll
  for (int p = 0; p < P; ++p) {
    int i = tid + p * T;
    float x = px[i * 3 + 0], y = px[i * 3 + 1], z = px[i * 3 + 2];
    bxy[i] = make_float2(x, y);
    bz[i] = z;
    mind[p] = 1e10f;
  }
  if (tid < 3) s_key[tid] = 0ull;
  if (tid == 0) {  // pick 0 is always index 0 (scan emits `last` before update)
    float* o = new_xyz + (size_t)b * S * 3;
    o[0] = px[0]; o[1] = px[1]; o[2] = px[2];
  }
  __syncthreads();   // also orders the planar-array writes (same workgroup)
  int last = 0;
  for (int it = 1; it < S; ++it) {
    float2 q2 = bxy[last];
    float qz = bz[last];
    float qx = q2.x, qy = q2.y;
    float bestv = -1.f; int besti = 0;
#pragma unroll
    for (int p = 0; p < P; ++p) {
      int i = tid + p * T;
      float2 xy = bxy[i];
      float z = bz[i];
      float dx = __fsub_rn(xy.x, qx);
      float dy = __fsub_rn(xy.y, qy);
      float dz = __fsub_rn(z, qz);
      float d = __fadd_rn(__fadd_rn(__fmul_rn(dx, dx), __fmul_rn(dy, dy)), __fmul_rn(dz, dz));
      float mo = fminf(mind[p], d);
      mind[p] = mo;
      // p ascending => index ascending within thread: keeps first max on ties
      if (mo > bestv) { bestv = mo; besti = i; }
    }
    // vals >= 0 so float bits are order-preserving as u32; inverted index
    // makes max-reduce pick the smallest index on value ties.
    unsigned long long key = ((unsigned long long)__float_as_uint(bestv) << 32)
                           | (unsigned long long)(0xFFFFFFFFu - (unsigned)besti);
#pragma unroll
    for (int off = 1; off < 64; off <<= 1) {
      unsigned long long o = __shfl_xor(key, off, 64);
      if (o > key) key = o;
    }
    if (lane == 0) atomicMax(&s_key[it % 3], key);
    // reset the slot for NEXT iter; its last readers are one barrier behind
    if (tid == 0) s_key[(it + 1) % 3] = 0ull;
    __syncthreads();
    unsigned long long wk = s_key[it % 3];
    last = (int)(0xFFFFFFFFu - (unsigned)(wk & 0xFFFFFFFFull));
    if (tid == 0) {
      float2 w2 = bxy[last];
      float wz = bz[last];
      float* o = new_xyz + ((size_t)b * S + it) * 3;
      o[0] = w2.x; o[1] = w2.y; o[2] = wz;
    }
  }
}

// ---------------------------------------------------------------------------
// Ball query: one wave per center; take the FIRST nsample indices (ascending)
// with d2 < r2 (== nsample smallest indices, matching top_k(-key)). Pad with
// the first hit (0 if no hits).
__global__ __launch_bounds__(256) void ballquery_kernel(const float* __restrict__ xyz,
    const float* __restrict__ centers, int* __restrict__ out_idx,
    int N, int S, int nsample, float r2) {
  int gw = (blockIdx.x * blockDim.x + threadIdx.x) >> 6;
  int lane = threadIdx.x & 63;
  int b = gw / S;
  int s = gw - b * S;
  const float* px = xyz + (size_t)b * N * 3;
  const float* cp = centers + ((size_t)b * S + s) * 3;
  float cx = cp[0], cy = cp[1], cz = cp[2];
  int* out = out_idx + ((size_t)b * S + s) * nsample;
  int cnt = 0;
  int firsti = 0;
  for (int base = 0; base < N; base += WAVE) {
    int i = base + lane;
    float dx = __fsub_rn(cx, px[i * 3 + 0]);
    float dy = __fsub_rn(cy, px[i * 3 + 1]);
    float dz = __fsub_rn(cz, px[i * 3 + 2]);
    float d = __fadd_rn(__fadd_rn(__fmul_rn(dx, dx), __fmul_rn(dy, dy)), __fmul_rn(dz, dz));
    bool hit = d < r2;
    unsigned long long m = __ballot(hit);
    if (hit) {
      int slot = cnt + __popcll(m & ((1ull << lane) - 1ull));
      if (slot < nsample) out[slot] = i;
    }
    if (cnt == 0 && m) firsti = base + __ffsll((unsigned long long)m) - 1;
    cnt += __popcll(m);
    if (cnt >= nsample) break;
  }
  for (int q = cnt + lane; q < nsample; q += WAVE) out[q] = firsti;
}

// ---------------------------------------------------------------------------
// Build X0 rows: [xyz[j]-center (3), feats[j] (ci)] for r=(b,s,k), c in [0,3+ci)
__global__ __launch_bounds__(256) void group_kernel(const float* __restrict__ xyz,
    const float* __restrict__ feats, const float* __restrict__ centers,
    const int* __restrict__ idx, float* __restrict__ X,
    int N, int S, int K, int ci, int R) {
  int t = blockIdx.x * blockDim.x + threadIdx.x;
  int C0 = ci + 3;
  int r = t / C0;
  if (r >= R) return;
  int c = t - r * C0;
  int g = r / K;          // b*S + s
  int b = g / S;
  int j = idx[r];
  float v;
  if (c < 3) v = __fsub_rn(xyz[((size_t)b * N + j) * 3 + c], centers[(size_t)g * 3 + c]);
  else       v = feats[((size_t)b * N + j) * ci + (c - 3)];
  X[(size_t)r * C0 + c] = v;
}

// ---------------------------------------------------------------------------
// Tiled f32 GEMM: Y(RxCo) = X(RxC) @ W(CxCo). R % 64 == 0 always; C/Co guarded.
#define BM 64
#define BN 64
#define BK 16
__global__ __launch_bounds__(256) void mm_kernel(const float* __restrict__ A,
    const float* __restrict__ W, float* __restrict__ Y, int R, int C, int Co) {
  __shared__ float As[BK][BM + 4];
  __shared__ float Bs[BK][BN + 4];
  int r0 = blockIdx.x * BM;
  int n0 = blockIdx.y * BN;
  int tid = threadIdx.x;
  int tx = tid & 15, ty = tid >> 4;
  float acc[4][4] = {};
  for (int k0 = 0; k0 < C; k0 += BK) {
#pragma unroll
    for (int u = 0; u < 4; ++u) {
      int lin = tid + u * 256;
      int row = lin >> 4;
      int cc = lin & 15;
      int c = k0 + cc;
      As[cc][row] = (c < C) ? A[(size_t)(r0 + row) * C + c] : 0.f;
    }
#pragma unroll
    for (int u = 0; u < 4; ++u) {
      int lin = tid + u * 256;
      int kk = lin >> 6;
      int n = lin & 63;
      int c = k0 + kk;
      Bs[kk][n] = (c < C && (n0 + n) < Co) ? W[(size_t)c * Co + n0 + n] : 0.f;
    }
    __syncthreads();
#pragma unroll
    for (int kk = 0; kk < BK; ++kk) {
      float a0[4], b0[4];
#pragma unroll
      for (int i = 0; i < 4; ++i) a0[i] = As[kk][ty * 4 + i];
#pragma unroll
      for (int jj = 0; jj < 4; ++jj) b0[jj] = Bs[kk][tx * 4 + jj];
#pragma unroll
      for (int i = 0; i < 4; ++i)
#pragma unroll
        for (int jj = 0; jj < 4; ++jj)
          acc[i][jj] = fmaf(a0[i], b0[jj], acc[i][jj]);
    }
    __syncthreads();
  }
#pragma unroll
  for (int i = 0; i < 4; ++i) {
    int r = r0 + ty * 4 + i;
#pragma unroll
    for (int jj = 0; jj < 4; ++jj) {
      int n = n0 + tx * 4 + jj;
      if (n < Co) Y[(size_t)r * Co + n] = acc[i][jj];
    }
  }
}

// ---------------------------------------------------------------------------
// Per-channel sum / sumsq over R rows into st[0..Co) and st[512..512+Co).
__global__ __launch_bounds__(256) void stats_kernel(const float* __restrict__ Y,
    float* __restrict__ st, int R, int Co) {
  __shared__ float s_sum[512], s_sq[512];
  for (int i = threadIdx.x; i < Co; i += 256) { s_sum[i] = 0.f; s_sq[i] = 0.f; }
  __syncthreads();
  int r0 = blockIdx.x * 512;
  int r1 = min(R, r0 + 512);
  if (Co <= 256) {
    int c = threadIdx.x & (Co - 1);
    int rstep = 256 / Co;
    int roff = threadIdx.x / Co;
    float ls = 0.f, lq = 0.f;
    for (int r = r0 + roff; r < r1; r += rstep) {
      float v = Y[(size_t)r * Co + c];
      ls += v; lq += v * v;
    }
    atomicAdd(&s_sum[c], ls); atomicAdd(&s_sq[c], lq);
  } else {  // Co == 512
    int c = threadIdx.x;
    float ls = 0.f, lq = 0.f, ls2 = 0.f, lq2 = 0.f;
    for (int r = r0; r < r1; ++r) {
      float v = Y[(size_t)r * 512 + c];
      float v2 = Y[(size_t)r * 512 + c + 256];
      ls += v; lq += v * v; ls2 += v2; lq2 += v2 * v2;
    }
    atomicAdd(&s_sum[c], ls); atomicAdd(&s_sq[c], lq);
    atomicAdd(&s_sum[c + 256], ls2); atomicAdd(&s_sq[c + 256], lq2);
  }
  __syncthreads();
  for (int i = threadIdx.x; i < Co; i += 256) {
    atomicAdd(&st[i], s_sum[i]);
    atomicAdd(&st[512 + i], s_sq[i]);
  }
}

// ---------------------------------------------------------------------------
// x = relu(gamma*(y-mu)*rsqrt(var+eps)+beta), mu/var from sums. In-place safe.
__global__ __launch_bounds__(256) void norm_relu_kernel(const float* Y,
    float* O, const float* __restrict__ st,
    const float* __restrict__ gamma, const float* __restrict__ beta,
    int total, int Co, float inv_n) {
  int t = blockIdx.x * blockDim.x + threadIdx.x;
  if (t >= total) return;
  int c = t & (Co - 1);
  float mu = st[c] * inv_n;
  float var = st[512 + c] * inv_n - mu * mu;
  float rs = rsqrtf(var + 1e-5f);
  float v = gamma[c] * ((Y[t] - mu) * rs) + beta[c];
  O[t] = v > 0.f ? v : 0.f;
}

// Last sub-layer: normalize+relu then max over the K samples of each group.
__global__ __launch_bounds__(256) void norm_relu_max_kernel(const float* __restrict__ Y,
    float* __restrict__ O, const float* __restrict__ st,
    const float* __restrict__ gamma, const float* __restrict__ beta,
    int G, int K, int Co, float inv_n) {
  int t = blockIdx.x * blockDim.x + threadIdx.x;
  if (t >= G * Co) return;
  int c = t & (Co - 1);
  int g = t / Co;
  float mu = st[c] * inv_n;
  float var = st[512 + c] * inv_n - mu * mu;
  float rs = rsqrtf(var + 1e-5f);
  float ga = gamma[c], be = beta[c];
  const float* yp = Y + (size_t)g * K * Co + c;
  float m = -1e30f;
  for (int k = 0; k < K; ++k) {
    float v = ga * ((yp[(size_t)k * Co] - mu) * rs) + be;
    m = fmaxf(m, v);
  }
  O[t] = m > 0.f ? m : 0.f;
}

// ---------------------------------------------------------------------------
extern "C" void kernel_launch(void* const* d_in, const int* in_sizes, int n_in,
                              void* d_out, int out_size, void* d_ws, size_t ws_size,
                              hipStream_t stream) {
  const float* pc = (const float*)d_in[0];
  float* out = (float*)d_out;
  char* wsb = (char*)d_ws;

  // ws layout: [0,1MB) ball idx; [1MB,+48KB) stats; [1.25MB,2.25MB) fps xy
  // planar; [2.25MB,2.75MB) fps z planar; [3MB,37MB) bufA; [37MB,70.5MB) bufB
  int* ballidx = (int*)wsb;
  float* stats = (float*)(wsb + ((size_t)1 << 20));
  float2* fps_xy = (float2*)(wsb + ((size_t)1280 << 10));
  float* fps_z = (float*)(wsb + ((size_t)2304 << 10));
  float* bufA = (float*)(wsb + ((size_t)3 << 20));
  float* bufB = (float*)(wsb + ((size_t)37 << 20));

  const int B = 8;
  static const int Ns[4] = {16384, 1024, 256, 64};
  static const int Ss[4] = {1024, 256, 64, 16};
  static const int Ks[4] = {32, 32, 16, 16};
  static const double Rr[4] = {0.02, 0.04, 0.06, 0.08};
  static const int Ci[4] = {3, 64, 128, 256};
  static const int mlp[4][4] = {{6,32,32,64},{67,64,64,128},{131,128,128,256},{259,256,256,512}};
  static const size_t ox[5] = {0, 393216, 417792, 423936, 425472};
  static const size_t of[5] = {425856, 819072, 1343360, 1605504, 1736576};

  split_kernel<<<(B * 16384 + 255) / 256, 256, 0, stream>>>(pc, out + ox[0], out + of[0], B * 16384);
  zero_kernel<<<(12 * 1024 + 255) / 256, 256, 0, stream>>>(stats, 12 * 1024);

  for (int l = 0; l < 4; ++l) {
    const float* xyz = out + ox[l];
    const float* fts = out + of[l];
    float* nxyz = out + ox[l + 1];
    const int N = Ns[l], S = Ss[l], K = Ks[l], ci = Ci[l], C0 = ci + 3;
    const float r2 = (float)(Rr[l] * Rr[l]);

    if (l == 0)      fps_kernel<16><<<B, 1024, 0, stream>>>(xyz, nxyz, fps_xy, fps_z, N, S);
    else if (l == 1) fps_kernel<1><<<B, 1024, 0, stream>>>(xyz, nxyz, fps_xy, fps_z, N, S);
    else if (l == 2) fps_kernel<1><<<B, 256, 0, stream>>>(xyz, nxyz, fps_xy, fps_z, N, S);
    else             fps_kernel<1><<<B, 64, 0, stream>>>(xyz, nxyz, fps_xy, fps_z, N, S);

    ballquery_kernel<<<(B * S) / 4, 256, 0, stream>>>(xyz, nxyz, ballidx, N, S, K, r2);

    const int R = B * S * K;
    {
      int total = R * C0;
      group_kernel<<<(total + 255) / 256, 256, 0, stream>>>(xyz, fts, nxyz, ballidx, bufA,
                                                            N, S, K, ci, R);
    }

    float* X = bufA; float* Y = bufB;
    for (int j = 0; j < 3; ++j) {
      const int cin = mlp[l][j], cout = mlp[l][j + 1];
      const float* Wt = (const float*)d_in[1 + (l * 3 + j) * 3 + 0];
      const float* Ga = (const float*)d_in[1 + (l * 3 + j) * 3 + 1];
      const float* Be = (const float*)d_in[1 + (l * 3 + j) * 3 + 2];
      dim3 grid(R / 64, (cout + 63) / 64);
      mm_kernel<<<grid, 256, 0, stream>>>(X, Wt, Y, R, cin, cout);
      float* st = stats + (size_t)(l * 3 + j) * 1024;
      stats_kernel<<<(R + 511) / 512, 256, 0, stream>>>(Y, st, R, cout);
      const float inv_n = 1.0f / (float)R;
      if (j < 2) {
        int tot = R * cout;
        norm_relu_kernel<<<(tot + 255) / 256, 256, 0, stream>>>(Y, Y, st, Ga, Be, tot, cout, inv_n);
        float* tswap = X; X = Y; Y = tswap;
      } else {
        int G = B * S;
        int tot = G * cout;
        norm_relu_max_kernel<<<(tot + 255) / 256, 256, 0, stream>>>(Y, out + of[l + 1], st, Ga, Be,
                                                                    G, K, cout, inv_n);
      }
    }
  }
}

// Round 4
// 3389.562 us; speedup vs baseline: 1.6189x; 1.6189x over previous
//
#include <hip/hip_runtime.h>

#define WAVE 64

// ---------------------------------------------------------------------------
// split pointcloud (B,N,6) -> xyz (B,N,3) + feats (B,N,3)
__global__ __launch_bounds__(256) void split_kernel(const float* __restrict__ pc,
    float* __restrict__ xyz, float* __restrict__ feats, int total) {
  int t = blockIdx.x * blockDim.x + threadIdx.x;
  if (t >= total) return;
  const float* p = pc + (size_t)t * 6;
  xyz[t * 3 + 0] = p[0]; xyz[t * 3 + 1] = p[1]; xyz[t * 3 + 2] = p[2];
  feats[t * 3 + 0] = p[3]; feats[t * 3 + 1] = p[4]; feats[t * 3 + 2] = p[5];
}

__global__ __launch_bounds__(256) void zero_kernel(float* __restrict__ p, int n) {
  int t = blockIdx.x * blockDim.x + threadIdx.x;
  if (t < n) p[t] = 0.f;
}

// ---------------------------------------------------------------------------
// Wave-wide reductions via DPP (VALU pipe only — no ds_swizzle LDS traffic).
// rocPRIM pattern: row_shr 1/2/4/8 + row_bcast15/31; full max lands in lane 63.
__device__ __forceinline__ float dpp_max_f32(float v) {
#define DPP_STEP_F(ctrl) { int t_ = __builtin_amdgcn_update_dpp( \
      __float_as_int(v), __float_as_int(v), ctrl, 0xf, 0xf, false); \
    v = fmaxf(v, __int_as_float(t_)); }
  DPP_STEP_F(0x111) DPP_STEP_F(0x112) DPP_STEP_F(0x114)
  DPP_STEP_F(0x118) DPP_STEP_F(0x142) DPP_STEP_F(0x143)
#undef DPP_STEP_F
  return v;  // valid in lane 63
}
__device__ __forceinline__ unsigned dpp_max_u32(unsigned v) {
#define DPP_STEP_U(ctrl) { unsigned t_ = (unsigned)__builtin_amdgcn_update_dpp( \
      (int)v, (int)v, ctrl, 0xf, 0xf, false); \
    v = (t_ > v) ? t_ : v; }
  DPP_STEP_U(0x111) DPP_STEP_U(0x112) DPP_STEP_U(0x114)
  DPP_STEP_U(0x118) DPP_STEP_U(0x142) DPP_STEP_U(0x143)
#undef DPP_STEP_U
  return v;  // valid in lane 63
}
__device__ __forceinline__ unsigned bcast63(unsigned v) {
  return (unsigned)__builtin_amdgcn_readlane((int)v, 63);
}

// Per-wave winner -> cross-wave combine: key = (f32 max bits << 32) | ~idx,
// u64 atomicMax across waves (3-slot rotation => ONE barrier per iteration;
// a slot's reset is two barriers away from its last read — proven round 3).
// Tie-break: vals >= 0 so f32 bits are order-preserving; inverted index makes
// max pick the smallest index, matching jnp.argmax first-occurrence.

// ---------------------------------------------------------------------------
// FPS, layer 0: N=16384, T=1024, P=16. Points live in VGPRs; the empty asm
// "pins" them — round-2/3 post-mortem: without it the allocator remats the
// coord loads from global every iteration (VGPR_Count=56 < 64 floats of
// state, tiny FETCH_SIZE => L2 re-reads). launch_bounds(1024,4) = 128-VGPR
// cap; ~90 live => no scratch spill.
// Exact semantics: ((dx*dx+dy*dy)+dz*dz) with explicit _rn ops (no FMA).
__global__ __launch_bounds__(1024, 4) void fps_big_kernel(const float* __restrict__ xyz,
    float* __restrict__ new_xyz, int N, int S) {
  const int b = blockIdx.x;
  const int tid = threadIdx.x;
  const int lane = tid & 63;
  const float* px = xyz + (size_t)b * N * 3;
  __shared__ unsigned long long s_key[3];
  float rx[16], ry[16], rz[16], mind[16];
#pragma unroll
  for (int p = 0; p < 16; ++p) {
    int i = tid + p * 1024;
    rx[p] = px[i * 3 + 0]; ry[p] = px[i * 3 + 1]; rz[p] = px[i * 3 + 2];
    asm volatile("" : "+v"(rx[p]), "+v"(ry[p]), "+v"(rz[p]));
    mind[p] = 1e10f;
  }
  if (tid < 3) s_key[tid] = 0ull;
  float qx = px[0], qy = px[1], qz = px[2];   // pick 0 is always index 0
  if (tid == 0) {
    float* o = new_xyz + (size_t)b * S * 3;
    o[0] = qx; o[1] = qy; o[2] = qz;
  }
  __syncthreads();
  for (unsigned it = 1; it < (unsigned)S; ++it) {
    float bestv = -1.f; unsigned besti = 0;
#pragma unroll
    for (int p = 0; p < 16; ++p) {
      float dx = __fsub_rn(rx[p], qx);
      float dy = __fsub_rn(ry[p], qy);
      float dz = __fsub_rn(rz[p], qz);
      float d = __fadd_rn(__fadd_rn(__fmul_rn(dx, dx), __fmul_rn(dy, dy)), __fmul_rn(dz, dz));
      float mo = fminf(mind[p], d);
      mind[p] = mo;
      // p ascending => index ascending within thread: keeps first max on ties
      if (mo > bestv) { bestv = mo; besti = (unsigned)(tid + p * 1024); }
    }
    float wm = dpp_max_f32(bestv);
    unsigned wmb = bcast63(__float_as_uint(wm));
    unsigned cand = (__float_as_uint(bestv) == wmb) ? (0xFFFFFFFFu - besti) : 0u;
    unsigned winv = bcast63(dpp_max_u32(cand));
    if (lane == 0) atomicMax(&s_key[it % 3u], ((unsigned long long)wmb << 32) | winv);
    if (tid == 0) s_key[(it + 1) % 3u] = 0ull;
    __syncthreads();
    unsigned long long k = s_key[it % 3u];
    int last = (int)(0xFFFFFFFFu - (unsigned)k);
    const float* q = px + (size_t)last * 3;  // broadcast L2 load
    qx = q[0]; qy = q[1]; qz = q[2];
    if (tid == 0) {
      float* o = new_xyz + ((size_t)b * S + it) * 3;
      o[0] = qx; o[1] = qy; o[2] = qz;
    }
  }
}

// ---------------------------------------------------------------------------
// FPS, layers 1-3: T=N<=1024, one point per thread (regs) + coords mirrored
// in LDS for the winner lookup (no global reads in the loop).
__global__ void fps_small_kernel(const float* __restrict__ xyz,
    float* __restrict__ new_xyz, int N, int S) {
  const int b = blockIdx.x;
  const int tid = threadIdx.x;
  const int lane = tid & 63;
  const float* px = xyz + (size_t)b * N * 3;
  __shared__ float sx[1024], sy[1024], sz[1024];
  __shared__ unsigned long long s_key[3];
  float x = px[tid * 3 + 0], y = px[tid * 3 + 1], z = px[tid * 3 + 2];
  sx[tid] = x; sy[tid] = y; sz[tid] = z;
  if (tid < 3) s_key[tid] = 0ull;
  float mind = 1e10f;
  float qx = px[0], qy = px[1], qz = px[2];
  if (tid == 0) {
    float* o = new_xyz + (size_t)b * S * 3;
    o[0] = qx; o[1] = qy; o[2] = qz;
  }
  __syncthreads();
  for (unsigned it = 1; it < (unsigned)S; ++it) {
    float dx = __fsub_rn(x, qx);
    float dy = __fsub_rn(y, qy);
    float dz = __fsub_rn(z, qz);
    float d = __fadd_rn(__fadd_rn(__fmul_rn(dx, dx), __fmul_rn(dy, dy)), __fmul_rn(dz, dz));
    mind = fminf(mind, d);
    float wm = dpp_max_f32(mind);
    unsigned wmb = bcast63(__float_as_uint(wm));
    unsigned cand = (__float_as_uint(mind) == wmb) ? (0xFFFFFFFFu - (unsigned)tid) : 0u;
    unsigned winv = bcast63(dpp_max_u32(cand));
    if (lane == 0) atomicMax(&s_key[it % 3u], ((unsigned long long)wmb << 32) | winv);
    if (tid == 0) s_key[(it + 1) % 3u] = 0ull;
    __syncthreads();
    unsigned long long k = s_key[it % 3u];
    int last = (int)(0xFFFFFFFFu - (unsigned)k);
    qx = sx[last]; qy = sy[last]; qz = sz[last];   // LDS broadcast
    if (tid == 0) {
      float* o = new_xyz + ((size_t)b * S + it) * 3;
      o[0] = qx; o[1] = qy; o[2] = qz;
    }
  }
}

// ---------------------------------------------------------------------------
// Ball query: one wave per center; take the FIRST nsample indices (ascending)
// with d2 < r2 (== nsample smallest indices, matching top_k(-key)). Pad with
// the first hit (0 if no hits).
__global__ __launch_bounds__(256) void ballquery_kernel(const float* __restrict__ xyz,
    const float* __restrict__ centers, int* __restrict__ out_idx,
    int N, int S, int nsample, float r2) {
  int gw = (blockIdx.x * blockDim.x + threadIdx.x) >> 6;
  int lane = threadIdx.x & 63;
  int b = gw / S;
  int s = gw - b * S;
  const float* px = xyz + (size_t)b * N * 3;
  const float* cp = centers + ((size_t)b * S + s) * 3;
  float cx = cp[0], cy = cp[1], cz = cp[2];
  int* out = out_idx + ((size_t)b * S + s) * nsample;
  int cnt = 0;
  int firsti = 0;
  for (int base = 0; base < N; base += WAVE) {
    int i = base + lane;
    float dx = __fsub_rn(cx, px[i * 3 + 0]);
    float dy = __fsub_rn(cy, px[i * 3 + 1]);
    float dz = __fsub_rn(cz, px[i * 3 + 2]);
    float d = __fadd_rn(__fadd_rn(__fmul_rn(dx, dx), __fmul_rn(dy, dy)), __fmul_rn(dz, dz));
    bool hit = d < r2;
    unsigned long long m = __ballot(hit);
    if (hit) {
      int slot = cnt + __popcll(m & ((1ull << lane) - 1ull));
      if (slot < nsample) out[slot] = i;
    }
    if (cnt == 0 && m) firsti = base + __ffsll((unsigned long long)m) - 1;
    cnt += __popcll(m);
    if (cnt >= nsample) break;
  }
  for (int q = cnt + lane; q < nsample; q += WAVE) out[q] = firsti;
}

// ---------------------------------------------------------------------------
// Build X0 rows: [xyz[j]-center (3), feats[j] (ci)] for r=(b,s,k), c in [0,3+ci)
__global__ __launch_bounds__(256) void group_kernel(const float* __restrict__ xyz,
    const float* __restrict__ feats, const float* __restrict__ centers,
    const int* __restrict__ idx, float* __restrict__ X,
    int N, int S, int K, int ci, int R) {
  int t = blockIdx.x * blockDim.x + threadIdx.x;
  int C0 = ci + 3;
  int r = t / C0;
  if (r >= R) return;
  int c = t - r * C0;
  int g = r / K;          // b*S + s
  int b = g / S;
  int j = idx[r];
  float v;
  if (c < 3) v = __fsub_rn(xyz[((size_t)b * N + j) * 3 + c], centers[(size_t)g * 3 + c]);
  else       v = feats[((size_t)b * N + j) * ci + (c - 3)];
  X[(size_t)r * C0 + c] = v;
}

// ---------------------------------------------------------------------------
// Tiled f32 GEMM: Y(RxCo) = X(RxC) @ W(CxCo). R % 64 == 0 always; C/Co guarded.
#define BM 64
#define BN 64
#define BK 16
__global__ __launch_bounds__(256) void mm_kernel(const float* __restrict__ A,
    const float* __restrict__ W, float* __restrict__ Y, int R, int C, int Co) {
  __shared__ float As[BK][BM + 4];
  __shared__ float Bs[BK][BN + 4];
  int r0 = blockIdx.x * BM;
  int n0 = blockIdx.y * BN;
  int tid = threadIdx.x;
  int tx = tid & 15, ty = tid >> 4;
  float acc[4][4] = {};
  for (int k0 = 0; k0 < C; k0 += BK) {
#pragma unroll
    for (int u = 0; u < 4; ++u) {
      int lin = tid + u * 256;
      int row = lin >> 4;
      int cc = lin & 15;
      int c = k0 + cc;
      As[cc][row] = (c < C) ? A[(size_t)(r0 + row) * C + c] : 0.f;
    }
#pragma unroll
    for (int u = 0; u < 4; ++u) {
      int lin = tid + u * 256;
      int kk = lin >> 6;
      int n = lin & 63;
      int c = k0 + kk;
      Bs[kk][n] = (c < C && (n0 + n) < Co) ? W[(size_t)c * Co + n0 + n] : 0.f;
    }
    __syncthreads();
#pragma unroll
    for (int kk = 0; kk < BK; ++kk) {
      float a0[4], b0[4];
#pragma unroll
      for (int i = 0; i < 4; ++i) a0[i] = As[kk][ty * 4 + i];
#pragma unroll
      for (int jj = 0; jj < 4; ++jj) b0[jj] = Bs[kk][tx * 4 + jj];
#pragma unroll
      for (int i = 0; i < 4; ++i)
#pragma unroll
        for (int jj = 0; jj < 4; ++jj)
          acc[i][jj] = fmaf(a0[i], b0[jj], acc[i][jj]);
    }
    __syncthreads();
  }
#pragma unroll
  for (int i = 0; i < 4; ++i) {
    int r = r0 + ty * 4 + i;
#pragma unroll
    for (int jj = 0; jj < 4; ++jj) {
      int n = n0 + tx * 4 + jj;
      if (n < Co) Y[(size_t)r * Co + n] = acc[i][jj];
    }
  }
}

// ---------------------------------------------------------------------------
// Per-channel sum / sumsq over R rows into st[0..Co) and st[512..512+Co).
__global__ __launch_bounds__(256) void stats_kernel(const float* __restrict__ Y,
    float* __restrict__ st, int R, int Co) {
  __shared__ float s_sum[512], s_sq[512];
  for (int i = threadIdx.x; i < Co; i += 256) { s_sum[i] = 0.f; s_sq[i] = 0.f; }
  __syncthreads();
  int r0 = blockIdx.x * 512;
  int r1 = min(R, r0 + 512);
  if (Co <= 256) {
    int c = threadIdx.x & (Co - 1);
    int rstep = 256 / Co;
    int roff = threadIdx.x / Co;
    float ls = 0.f, lq = 0.f;
    for (int r = r0 + roff; r < r1; r += rstep) {
      float v = Y[(size_t)r * Co + c];
      ls += v; lq += v * v;
    }
    atomicAdd(&s_sum[c], ls); atomicAdd(&s_sq[c], lq);
  } else {  // Co == 512
    int c = threadIdx.x;
    float ls = 0.f, lq = 0.f, ls2 = 0.f, lq2 = 0.f;
    for (int r = r0; r < r1; ++r) {
      float v = Y[(size_t)r * 512 + c];
      float v2 = Y[(size_t)r * 512 + c + 256];
      ls += v; lq += v * v; ls2 += v2; lq2 += v2 * v2;
    }
    atomicAdd(&s_sum[c], ls); atomicAdd(&s_sq[c], lq);
    atomicAdd(&s_sum[c + 256], ls2); atomicAdd(&s_sq[c + 256], lq2);
  }
  __syncthreads();
  for (int i = threadIdx.x; i < Co; i += 256) {
    atomicAdd(&st[i], s_sum[i]);
    atomicAdd(&st[512 + i], s_sq[i]);
  }
}

// ---------------------------------------------------------------------------
// x = relu(gamma*(y-mu)*rsqrt(var+eps)+beta), mu/var from sums. In-place safe.
__global__ __launch_bounds__(256) void norm_relu_kernel(const float* Y,
    float* O, const float* __restrict__ st,
    const float* __restrict__ gamma, const float* __restrict__ beta,
    int total, int Co, float inv_n) {
  int t = blockIdx.x * blockDim.x + threadIdx.x;
  if (t >= total) return;
  int c = t & (Co - 1);
  float mu = st[c] * inv_n;
  float var = st[512 + c] * inv_n - mu * mu;
  float rs = rsqrtf(var + 1e-5f);
  float v = gamma[c] * ((Y[t] - mu) * rs) + beta[c];
  O[t] = v > 0.f ? v : 0.f;
}

// Last sub-layer: normalize+relu then max over the K samples of each group.
__global__ __launch_bounds__(256) void norm_relu_max_kernel(const float* __restrict__ Y,
    float* __restrict__ O, const float* __restrict__ st,
    const float* __restrict__ gamma, const float* __restrict__ beta,
    int G, int K, int Co, float inv_n) {
  int t = blockIdx.x * blockDim.x + threadIdx.x;
  if (t >= G * Co) return;
  int c = t & (Co - 1);
  int g = t / Co;
  float mu = st[c] * inv_n;
  float var = st[512 + c] * inv_n - mu * mu;
  float rs = rsqrtf(var + 1e-5f);
  float ga = gamma[c], be = beta[c];
  const float* yp = Y + (size_t)g * K * Co + c;
  float m = -1e30f;
  for (int k = 0; k < K; ++k) {
    float v = ga * ((yp[(size_t)k * Co] - mu) * rs) + be;
    m = fmaxf(m, v);
  }
  O[t] = m > 0.f ? m : 0.f;
}

// ---------------------------------------------------------------------------
extern "C" void kernel_launch(void* const* d_in, const int* in_sizes, int n_in,
                              void* d_out, int out_size, void* d_ws, size_t ws_size,
                              hipStream_t stream) {
  const float* pc = (const float*)d_in[0];
  float* out = (float*)d_out;
  char* wsb = (char*)d_ws;

  // ws layout: [0,1MB) ball idx; [1MB,+48KB) stats; [3MB,37MB) bufA; [37MB,104MB) bufB
  int* ballidx = (int*)wsb;
  float* stats = (float*)(wsb + ((size_t)1 << 20));
  float* bufA = (float*)(wsb + ((size_t)3 << 20));
  float* bufB = (float*)(wsb + ((size_t)37 << 20));

  const int B = 8;
  static const int Ns[4] = {16384, 1024, 256, 64};
  static const int Ss[4] = {1024, 256, 64, 16};
  static const int Ks[4] = {32, 32, 16, 16};
  static const double Rr[4] = {0.02, 0.04, 0.06, 0.08};
  static const int Ci[4] = {3, 64, 128, 256};
  static const int mlp[4][4] = {{6,32,32,64},{67,64,64,128},{131,128,128,256},{259,256,256,512}};
  static const size_t ox[5] = {0, 393216, 417792, 423936, 425472};
  static const size_t of[5] = {425856, 819072, 1343360, 1605504, 1736576};

  split_kernel<<<(B * 16384 + 255) / 256, 256, 0, stream>>>(pc, out + ox[0], out + of[0], B * 16384);
  zero_kernel<<<(12 * 1024 + 255) / 256, 256, 0, stream>>>(stats, 12 * 1024);

  for (int l = 0; l < 4; ++l) {
    const float* xyz = out + ox[l];
    const float* fts = out + of[l];
    float* nxyz = out + ox[l + 1];
    const int N = Ns[l], S = Ss[l], K = Ks[l], ci = Ci[l], C0 = ci + 3;
    const float r2 = (float)(Rr[l] * Rr[l]);

    if (l == 0) fps_big_kernel<<<B, 1024, 0, stream>>>(xyz, nxyz, N, S);
    else        fps_small_kernel<<<B, N, 0, stream>>>(xyz, nxyz, N, S);

    ballquery_kernel<<<(B * S) / 4, 256, 0, stream>>>(xyz, nxyz, ballidx, N, S, K, r2);

    const int R = B * S * K;
    {
      int total = R * C0;
      group_kernel<<<(total + 255) / 256, 256, 0, stream>>>(xyz, fts, nxyz, ballidx, bufA,
                                                            N, S, K, ci, R);
    }

    float* X = bufA; float* Y = bufB;
    for (int j = 0; j < 3; ++j) {
      const int cin = mlp[l][j], cout = mlp[l][j + 1];
      const float* Wt = (const float*)d_in[1 + (l * 3 + j) * 3 + 0];
      const float* Ga = (const float*)d_in[1 + (l * 3 + j) * 3 + 1];
      const float* Be = (const float*)d_in[1 + (l * 3 + j) * 3 + 2];
      dim3 grid(R / 64, (cout + 63) / 64);
      mm_kernel<<<grid, 256, 0, stream>>>(X, Wt, Y, R, cin, cout);
      float* st = stats + (size_t)(l * 3 + j) * 1024;
      stats_kernel<<<(R + 511) / 512, 256, 0, stream>>>(Y, st, R, cout);
      const float inv_n = 1.0f / (float)R;
      if (j < 2) {
        int tot = R * cout;
        norm_relu_kernel<<<(tot + 255) / 256, 256, 0, stream>>>(Y, Y, st, Ga, Be, tot, cout, inv_n);
        float* tswap = X; X = Y; Y = tswap;
      } else {
        int G = B * S;
        int tot = G * cout;
        norm_relu_max_kernel<<<(tot + 255) / 256, 256, 0, stream>>>(Y, out + of[l + 1], st, Ga, Be,
                                                                    G, K, cout, inv_n);
      }
    }
  }
}

// Round 5
// 2795.684 us; speedup vs baseline: 1.9628x; 1.2124x over previous
//
#include <hip/hip_runtime.h>

#define WAVE 64

// ---------------------------------------------------------------------------
// split pointcloud (B,N,6) -> xyz (B,N,3) + feats (B,N,3)
__global__ __launch_bounds__(256) void split_kernel(const float* __restrict__ pc,
    float* __restrict__ xyz, float* __restrict__ feats, int total) {
  int t = blockIdx.x * blockDim.x + threadIdx.x;
  if (t >= total) return;
  const float* p = pc + (size_t)t * 6;
  xyz[t * 3 + 0] = p[0]; xyz[t * 3 + 1] = p[1]; xyz[t * 3 + 2] = p[2];
  feats[t * 3 + 0] = p[3]; feats[t * 3 + 1] = p[4]; feats[t * 3 + 2] = p[5];
}

__global__ __launch_bounds__(256) void zero_kernel(float* __restrict__ p, int n) {
  int t = blockIdx.x * blockDim.x + threadIdx.x;
  if (t < n) p[t] = 0.f;
}

// ---------------------------------------------------------------------------
// Wave-wide reductions via DPP (VALU pipe only — no ds_swizzle LDS traffic).
// rocPRIM pattern: row_shr 1/2/4/8 + row_bcast15/31; full max lands in lane 63.
__device__ __forceinline__ float dpp_max_f32(float v) {
#define DPP_STEP_F(ctrl) { int t_ = __builtin_amdgcn_update_dpp( \
      __float_as_int(v), __float_as_int(v), ctrl, 0xf, 0xf, false); \
    v = fmaxf(v, __int_as_float(t_)); }
  DPP_STEP_F(0x111) DPP_STEP_F(0x112) DPP_STEP_F(0x114)
  DPP_STEP_F(0x118) DPP_STEP_F(0x142) DPP_STEP_F(0x143)
#undef DPP_STEP_F
  return v;  // valid in lane 63
}
__device__ __forceinline__ unsigned dpp_max_u32(unsigned v) {
#define DPP_STEP_U(ctrl) { unsigned t_ = (unsigned)__builtin_amdgcn_update_dpp( \
      (int)v, (int)v, ctrl, 0xf, 0xf, false); \
    v = (t_ > v) ? t_ : v; }
  DPP_STEP_U(0x111) DPP_STEP_U(0x112) DPP_STEP_U(0x114)
  DPP_STEP_U(0x118) DPP_STEP_U(0x142) DPP_STEP_U(0x143)
#undef DPP_STEP_U
  return v;  // valid in lane 63
}
__device__ __forceinline__ unsigned bcast63(unsigned v) {
  return (unsigned)__builtin_amdgcn_readlane((int)v, 63);
}

// ---------------------------------------------------------------------------
// FPS, layer 0: N=16384, T=1024, P=16. Points pinned into the unified
// VGPR/AGPR file via empty asm (round-4 counters: VGPR=48 + coords in AGPRs,
// VALUBusy at 90% of the 8-CU ceiling => VALU-bound, near structural floor).
// Exact semantics: ((dx*dx+dy*dy)+dz*dz) with explicit _rn ops (no FMA).
__global__ __launch_bounds__(1024, 4) void fps_big_kernel(const float* __restrict__ xyz,
    float* __restrict__ new_xyz, int N, int S) {
  const int b = blockIdx.x;
  const int tid = threadIdx.x;
  const int lane = tid & 63;
  const float* px = xyz + (size_t)b * N * 3;
  __shared__ unsigned long long s_key[3];
  float rx[16], ry[16], rz[16], mind[16];
#pragma unroll
  for (int p = 0; p < 16; ++p) {
    int i = tid + p * 1024;
    rx[p] = px[i * 3 + 0]; ry[p] = px[i * 3 + 1]; rz[p] = px[i * 3 + 2];
    asm volatile("" : "+v"(rx[p]), "+v"(ry[p]), "+v"(rz[p]));
    mind[p] = 1e10f;
  }
  if (tid < 3) s_key[tid] = 0ull;
  float qx = px[0], qy = px[1], qz = px[2];   // pick 0 is always index 0
  if (tid == 0) {
    float* o = new_xyz + (size_t)b * S * 3;
    o[0] = qx; o[1] = qy; o[2] = qz;
  }
  __syncthreads();
  for (unsigned it = 1; it < (unsigned)S; ++it) {
    float bestv = -1.f; unsigned besti = 0;
#pragma unroll
    for (int p = 0; p < 16; ++p) {
      float dx = __fsub_rn(rx[p], qx);
      float dy = __fsub_rn(ry[p], qy);
      float dz = __fsub_rn(rz[p], qz);
      float d = __fadd_rn(__fadd_rn(__fmul_rn(dx, dx), __fmul_rn(dy, dy)), __fmul_rn(dz, dz));
      float mo = fminf(mind[p], d);
      mind[p] = mo;
      // p ascending => index ascending within thread: keeps first max on ties
      if (mo > bestv) { bestv = mo; besti = (unsigned)(tid + p * 1024); }
    }
    float wm = dpp_max_f32(bestv);
    unsigned wmb = bcast63(__float_as_uint(wm));
    unsigned cand = (__float_as_uint(bestv) == wmb) ? (0xFFFFFFFFu - besti) : 0u;
    unsigned winv = bcast63(dpp_max_u32(cand));
    if (lane == 0) atomicMax(&s_key[it % 3u], ((unsigned long long)wmb << 32) | winv);
    if (tid == 0) s_key[(it + 1) % 3u] = 0ull;
    __syncthreads();
    unsigned long long k = s_key[it % 3u];
    int last = (int)(0xFFFFFFFFu - (unsigned)k);
    const float* q = px + (size_t)last * 3;  // broadcast L2 load
    qx = q[0]; qy = q[1]; qz = q[2];
    if (tid == 0) {
      float* o = new_xyz + ((size_t)b * S + it) * 3;
      o[0] = qx; o[1] = qy; o[2] = qz;
    }
  }
}

// ---------------------------------------------------------------------------
// FPS, layers 1-3: T=N<=1024, one point per thread (regs) + coords mirrored
// in LDS for the winner lookup (no global reads in the loop).
__global__ void fps_small_kernel(const float* __restrict__ xyz,
    float* __restrict__ new_xyz, int N, int S) {
  const int b = blockIdx.x;
  const int tid = threadIdx.x;
  const int lane = tid & 63;
  const float* px = xyz + (size_t)b * N * 3;
  __shared__ float sx[1024], sy[1024], sz[1024];
  __shared__ unsigned long long s_key[3];
  float x = px[tid * 3 + 0], y = px[tid * 3 + 1], z = px[tid * 3 + 2];
  sx[tid] = x; sy[tid] = y; sz[tid] = z;
  if (tid < 3) s_key[tid] = 0ull;
  float mind = 1e10f;
  float qx = px[0], qy = px[1], qz = px[2];
  if (tid == 0) {
    float* o = new_xyz + (size_t)b * S * 3;
    o[0] = qx; o[1] = qy; o[2] = qz;
  }
  __syncthreads();
  for (unsigned it = 1; it < (unsigned)S; ++it) {
    float dx = __fsub_rn(x, qx);
    float dy = __fsub_rn(y, qy);
    float dz = __fsub_rn(z, qz);
    float d = __fadd_rn(__fadd_rn(__fmul_rn(dx, dx), __fmul_rn(dy, dy)), __fmul_rn(dz, dz));
    mind = fminf(mind, d);
    float wm = dpp_max_f32(mind);
    unsigned wmb = bcast63(__float_as_uint(wm));
    unsigned cand = (__float_as_uint(mind) == wmb) ? (0xFFFFFFFFu - (unsigned)tid) : 0u;
    unsigned winv = bcast63(dpp_max_u32(cand));
    if (lane == 0) atomicMax(&s_key[it % 3u], ((unsigned long long)wmb << 32) | winv);
    if (tid == 0) s_key[(it + 1) % 3u] = 0ull;
    __syncthreads();
    unsigned long long k = s_key[it % 3u];
    int last = (int)(0xFFFFFFFFu - (unsigned)k);
    qx = sx[last]; qy = sy[last]; qz = sz[last];   // LDS broadcast
    if (tid == 0) {
      float* o = new_xyz + ((size_t)b * S + it) * 3;
      o[0] = qx; o[1] = qy; o[2] = qz;
    }
  }
}

// ---------------------------------------------------------------------------
// Ball query: one wave per center; take the FIRST nsample indices (ascending)
// with d2 < r2 (== nsample smallest indices, matching top_k(-key)). Pad with
// the first hit (0 if no hits).
__global__ __launch_bounds__(256) void ballquery_kernel(const float* __restrict__ xyz,
    const float* __restrict__ centers, int* __restrict__ out_idx,
    int N, int S, int nsample, float r2) {
  int gw = (blockIdx.x * blockDim.x + threadIdx.x) >> 6;
  int lane = threadIdx.x & 63;
  int b = gw / S;
  int s = gw - b * S;
  const float* px = xyz + (size_t)b * N * 3;
  const float* cp = centers + ((size_t)b * S + s) * 3;
  float cx = cp[0], cy = cp[1], cz = cp[2];
  int* out = out_idx + ((size_t)b * S + s) * nsample;
  int cnt = 0;
  int firsti = 0;
  for (int base = 0; base < N; base += WAVE) {
    int i = base + lane;
    float dx = __fsub_rn(cx, px[i * 3 + 0]);
    float dy = __fsub_rn(cy, px[i * 3 + 1]);
    float dz = __fsub_rn(cz, px[i * 3 + 2]);
    float d = __fadd_rn(__fadd_rn(__fmul_rn(dx, dx), __fmul_rn(dy, dy)), __fmul_rn(dz, dz));
    bool hit = d < r2;
    unsigned long long m = __ballot(hit);
    if (hit) {
      int slot = cnt + __popcll(m & ((1ull << lane) - 1ull));
      if (slot < nsample) out[slot] = i;
    }
    if (cnt == 0 && m) firsti = base + __ffsll((unsigned long long)m) - 1;
    cnt += __popcll(m);
    if (cnt >= nsample) break;
  }
  for (int q = cnt + lane; q < nsample; q += WAVE) out[q] = firsti;
}

// ---------------------------------------------------------------------------
// Build X0 rows: [xyz[j]-center (3), feats[j] (ci)] for r=(b,s,k), c in [0,3+ci)
__global__ __launch_bounds__(256) void group_kernel(const float* __restrict__ xyz,
    const float* __restrict__ feats, const float* __restrict__ centers,
    const int* __restrict__ idx, float* __restrict__ X,
    int N, int S, int K, int ci, int R) {
  int t = blockIdx.x * blockDim.x + threadIdx.x;
  int C0 = ci + 3;
  int r = t / C0;
  if (r >= R) return;
  int c = t - r * C0;
  int g = r / K;          // b*S + s
  int b = g / S;
  int j = idx[r];
  float v;
  if (c < 3) v = __fsub_rn(xyz[((size_t)b * N + j) * 3 + c], centers[(size_t)g * 3 + c]);
  else       v = feats[((size_t)b * N + j) * ci + (c - 3)];
  X[(size_t)r * C0 + c] = v;
}

// ---------------------------------------------------------------------------
// Fused tiled f32 GEMM: Y(RxCo) = normReLU(A)(RxC) @ W(CxCo).
//  - if st_in != nullptr, A is normalized elementwise during LDS staging:
//      v = relu(gamma_in[c]*((a - mu[c])*rs[c]) + beta_in[c])
//    with mu/rs from st_in (prev sub-layer's sums; complete by stream order).
//  - per-channel sum/sumsq of Y accumulated into st_out (epilogue atomics)
//    -> replaces the separate stats pass (round-4 fusion).
// R % 64 == 0 always; C/Co guarded.
#define BM 64
#define BN 64
#define BK 16
__global__ __launch_bounds__(256) void mm_fused_kernel(const float* __restrict__ A,
    const float* __restrict__ W, float* __restrict__ Y,
    float* __restrict__ st_out, const float* __restrict__ st_in,
    const float* __restrict__ g_in, const float* __restrict__ b_in,
    int R, int C, int Co, float inv_n) {
  __shared__ float As[BK][BM + 4];
  __shared__ float Bs[BK][BN + 4];
  __shared__ float s_mu[260], s_rs[260], s_g[260], s_b[260];
  __shared__ float s_sum[BN], s_sq[BN];
  int r0 = blockIdx.x * BM;
  int n0 = blockIdx.y * BN;
  int tid = threadIdx.x;
  int tx = tid & 15, ty = tid >> 4;
  if (st_in) {
    for (int c = tid; c < C; c += 256) {
      float mu = st_in[c] * inv_n;
      float var = st_in[512 + c] * inv_n - mu * mu;
      s_mu[c] = mu; s_rs[c] = rsqrtf(var + 1e-5f);
      s_g[c] = g_in[c]; s_b[c] = b_in[c];
    }
  }
  if (tid < BN) { s_sum[tid] = 0.f; s_sq[tid] = 0.f; }
  __syncthreads();
  float acc[4][4] = {};
  for (int k0 = 0; k0 < C; k0 += BK) {
#pragma unroll
    for (int u = 0; u < 4; ++u) {
      int lin = tid + u * 256;
      int row = lin >> 4;
      int cc = lin & 15;
      int c = k0 + cc;
      float v = 0.f;
      if (c < C) {
        v = A[(size_t)(r0 + row) * C + c];
        if (st_in) {
          v = s_g[c] * ((v - s_mu[c]) * s_rs[c]) + s_b[c];
          v = v > 0.f ? v : 0.f;
        }
      }
      As[cc][row] = v;
    }
#pragma unroll
    for (int u = 0; u < 4; ++u) {
      int lin = tid + u * 256;
      int kk = lin >> 6;
      int n = lin & 63;
      int c = k0 + kk;
      Bs[kk][n] = (c < C && (n0 + n) < Co) ? W[(size_t)c * Co + n0 + n] : 0.f;
    }
    __syncthreads();
#pragma unroll
    for (int kk = 0; kk < BK; ++kk) {
      float a0[4], b0[4];
#pragma unroll
      for (int i = 0; i < 4; ++i) a0[i] = As[kk][ty * 4 + i];
#pragma unroll
      for (int jj = 0; jj < 4; ++jj) b0[jj] = Bs[kk][tx * 4 + jj];
#pragma unroll
      for (int i = 0; i < 4; ++i)
#pragma unroll
        for (int jj = 0; jj < 4; ++jj)
          acc[i][jj] = fmaf(a0[i], b0[jj], acc[i][jj]);
    }
    __syncthreads();
  }
#pragma unroll
  for (int i = 0; i < 4; ++i) {
    int r = r0 + ty * 4 + i;
#pragma unroll
    for (int jj = 0; jj < 4; ++jj) {
      int n = n0 + tx * 4 + jj;
      if (n < Co) Y[(size_t)r * Co + n] = acc[i][jj];
    }
  }
  // epilogue: per-column sum/sumsq of this block's tile -> LDS -> global
#pragma unroll
  for (int jj = 0; jj < 4; ++jj) {
    float cs = 0.f, cq = 0.f;
#pragma unroll
    for (int i = 0; i < 4; ++i) { float v = acc[i][jj]; cs += v; cq += v * v; }
    atomicAdd(&s_sum[tx * 4 + jj], cs);
    atomicAdd(&s_sq[tx * 4 + jj], cq);
  }
  __syncthreads();
  if (tid < BN) {
    int n = n0 + tid;
    if (n < Co) {
      atomicAdd(&st_out[n], s_sum[tid]);
      atomicAdd(&st_out[512 + n], s_sq[tid]);
    }
  }
}

// Last sub-layer: normalize+relu then max over the K samples of each group.
__global__ __launch_bounds__(256) void norm_relu_max_kernel(const float* __restrict__ Y,
    float* __restrict__ O, const float* __restrict__ st,
    const float* __restrict__ gamma, const float* __restrict__ beta,
    int G, int K, int Co, float inv_n) {
  int t = blockIdx.x * blockDim.x + threadIdx.x;
  if (t >= G * Co) return;
  int c = t & (Co - 1);
  int g = t / Co;
  float mu = st[c] * inv_n;
  float var = st[512 + c] * inv_n - mu * mu;
  float rs = rsqrtf(var + 1e-5f);
  float ga = gamma[c], be = beta[c];
  const float* yp = Y + (size_t)g * K * Co + c;
  float m = -1e30f;
  for (int k = 0; k < K; ++k) {
    float v = ga * ((yp[(size_t)k * Co] - mu) * rs) + be;
    m = fmaxf(m, v);
  }
  O[t] = m > 0.f ? m : 0.f;
}

// ---------------------------------------------------------------------------
extern "C" void kernel_launch(void* const* d_in, const int* in_sizes, int n_in,
                              void* d_out, int out_size, void* d_ws, size_t ws_size,
                              hipStream_t stream) {
  const float* pc = (const float*)d_in[0];
  float* out = (float*)d_out;
  char* wsb = (char*)d_ws;

  // ws layout: [0,1MB) ball idx; [1MB,+48KB) stats; [3MB,37MB) bufA; [37MB,104MB) bufB
  int* ballidx = (int*)wsb;
  float* stats = (float*)(wsb + ((size_t)1 << 20));
  float* bufA = (float*)(wsb + ((size_t)3 << 20));
  float* bufB = (float*)(wsb + ((size_t)37 << 20));

  const int B = 8;
  static const int Ns[4] = {16384, 1024, 256, 64};
  static const int Ss[4] = {1024, 256, 64, 16};
  static const int Ks[4] = {32, 32, 16, 16};
  static const double Rr[4] = {0.02, 0.04, 0.06, 0.08};
  static const int Ci[4] = {3, 64, 128, 256};
  static const int mlp[4][4] = {{6,32,32,64},{67,64,64,128},{131,128,128,256},{259,256,256,512}};
  static const size_t ox[5] = {0, 393216, 417792, 423936, 425472};
  static const size_t of[5] = {425856, 819072, 1343360, 1605504, 1736576};

  split_kernel<<<(B * 16384 + 255) / 256, 256, 0, stream>>>(pc, out + ox[0], out + of[0], B * 16384);
  zero_kernel<<<(12 * 1024 + 255) / 256, 256, 0, stream>>>(stats, 12 * 1024);

  for (int l = 0; l < 4; ++l) {
    const float* xyz = out + ox[l];
    const float* fts = out + of[l];
    float* nxyz = out + ox[l + 1];
    const int N = Ns[l], S = Ss[l], K = Ks[l], ci = Ci[l], C0 = ci + 3;
    const float r2 = (float)(Rr[l] * Rr[l]);

    if (l == 0) fps_big_kernel<<<B, 1024, 0, stream>>>(xyz, nxyz, N, S);
    else        fps_small_kernel<<<B, N, 0, stream>>>(xyz, nxyz, N, S);

    ballquery_kernel<<<(B * S) / 4, 256, 0, stream>>>(xyz, nxyz, ballidx, N, S, K, r2);

    const int R = B * S * K;
    {
      int total = R * C0;
      group_kernel<<<(total + 255) / 256, 256, 0, stream>>>(xyz, fts, nxyz, ballidx, bufA,
                                                            N, S, K, ci, R);
    }

    const float inv_n = 1.0f / (float)R;
    float* X = bufA; float* Y = bufB;
    const float* prev_st = nullptr;
    const float* prev_g = nullptr;
    const float* prev_b = nullptr;
    for (int j = 0; j < 3; ++j) {
      const int cin = mlp[l][j], cout = mlp[l][j + 1];
      const float* Wt = (const float*)d_in[1 + (l * 3 + j) * 3 + 0];
      const float* Ga = (const float*)d_in[1 + (l * 3 + j) * 3 + 1];
      const float* Be = (const float*)d_in[1 + (l * 3 + j) * 3 + 2];
      float* st = stats + (size_t)(l * 3 + j) * 1024;
      dim3 grid(R / 64, (cout + 63) / 64);
      mm_fused_kernel<<<grid, 256, 0, stream>>>(X, Wt, Y, st, prev_st, prev_g, prev_b,
                                                R, cin, cout, inv_n);
      if (j < 2) {
        prev_st = st; prev_g = Ga; prev_b = Be;
        float* tswap = X; X = Y; Y = tswap;
      } else {
        int G = B * S;
        int tot = G * cout;
        norm_relu_max_kernel<<<(tot + 255) / 256, 256, 0, stream>>>(Y, out + of[l + 1], st, Ga, Be,
                                                                    G, K, cout, inv_n);
      }
    }
  }
}